// Round 8
// baseline (506.729 us; speedup 1.0000x reference)
//
#include <hip/hip_runtime.h>
#include <hip/hip_bf16.h>

#define T_SEQ 256
#define BATCH 1024

typedef __attribute__((ext_vector_type(8))) short  short8;   // 8 bf16 (x32 MFMA frag)
typedef __attribute__((ext_vector_type(4))) float  floatx4;  // MFMA C/D frag
typedef unsigned short ushort_t;
typedef unsigned int   uint_t;

template <int P> struct IC { static constexpr int v = P; };

constexpr float NL2E = -1.4426950408889634f;   // -log2(e): sigmoid = rcp(1+exp2(z))
constexpr float L2E2 =  2.8853900817779268f;   // 2*log2(e): tanh = 1-2*rcp(1+exp2(x))

__device__ __forceinline__ float exp2_fast(float x) {
    float r; asm("v_exp_f32 %0, %1" : "=v"(r) : "v"(x)); return r;
}
__device__ __forceinline__ float rcp_fast(float x) {
    float r; asm("v_rcp_f32 %0, %1" : "=v"(r) : "v"(x)); return r;
}
__device__ __forceinline__ ushort_t f2bf(float f) {
    union { float f; uint_t u; } v; v.f = f;
    uint_t r = v.u + 0x7FFFu + ((v.u >> 16) & 1u);   // RNE
    return (ushort_t)(r >> 16);
}
__device__ __forceinline__ uint_t pk_bf16(float a, float b) {
    union { __hip_bfloat162 h; uint_t u; } v;
    v.h = __float22bfloat162_rn(make_float2(a, b));
    return v.u;
}
// Barrier WITHOUT vmcnt drain: LDS ordering only; global loads/stores stay in flight.
__device__ __forceinline__ void sync_lds() {
    asm volatile("s_waitcnt lgkmcnt(0)\n\ts_barrier" ::: "memory");
}

// ============================= Ledger (measured) ==================================
// L1: CLASSIC 4-wave PLAIN = 170.8/171.1 (R3/R7) = BEST. grouped 182 (R6), SWAP 200.
// L2: SWAP-LDS 2-wave grouped ~118 (R6) = BEST.
// L3: SWAP-LDS 1-wave grouped ~196 (R6) = BEST. plain 207 (R3), REGH 199 (R1),
//     dual 212 (R4), xz-hoist 220 (R5), bpermute ~214 (R7).
// Falsified chain theories: chain-split acc (R4, +115), xz-hoist (R5, null),
// bpermute h-exchange (R7, +18). Dual (R4): +100% work/wave = +3% time.
// CONCLUSION: per-step floor is serial MFMA+trans latency + fixed overhead at
// ~1 wave/SIMD; exchange mechanism & instruction count are NOT on the margin.
// Only per-layer {mode, waves, act-style} choices moved the needle.
// R8 = first simultaneous combination of all three per-layer bests.
// =================================================================================

// 4 sigmoids from 4 prescaled logits with ONE rcp:
// A_r = 1+exp2(z_r); R=rcp(A0A1A2A3); 1/A0 = R*A1*(A2A3), etc.
__device__ __forceinline__ void sig4(const float z[4], float o[4]) {
    const float A0 = 1.0f + exp2_fast(z[0]);
    const float A1 = 1.0f + exp2_fast(z[1]);
    const float A2 = 1.0f + exp2_fast(z[2]);
    const float A3 = 1.0f + exp2_fast(z[3]);
    const float P01 = A0 * A1, P23 = A2 * A3;
    const float R   = rcp_fast(P01 * P23);
    const float R01 = R * P23;      // = 1/(A0*A1)
    const float R23 = R * P01;      // = 1/(A2*A3)
    o[0] = R01 * A1; o[1] = R01 * A0;
    o[2] = R23 * A3; o[3] = R23 * A2;
}
// 4 tanhs (arg prescaled by 2log2e): tanh = 1 - 2*sigmoid'(x)
__device__ __forceinline__ void tanh4(const float z[4], float o[4]) {
    float s[4]; sig4(z, s);
#pragma unroll
    for (int r = 0; r < 4; r++) o[r] = fmaf(-2.0f, s[r], 1.0f);
}

// Fused persistent LSTM layer. MODE: 0=classic, 1=swap. ACT: 0=plain rcp, 1=grouped.
template <int D, int H, bool IS_FIRST, bool SEQ_OUT, int MODE, int ACT>
__global__ __launch_bounds__(64 * (H / 16), 1) void lstm_fused(
    const void* __restrict__ xin,
    const float* __restrict__ Wf, const float* __restrict__ Uf, const float* __restrict__ bgf,
    const float* __restrict__ Wb, const float* __restrict__ Ub, const float* __restrict__ bgb,
    void* __restrict__ outp)
{
    constexpr bool SW = (MODE >= 1);             // swapped operand order
    constexpr int UG  = H / 16;                  // waves per block
    constexpr int KSx = D / 32;                  // x k-chunks (16x16x32)
    constexpr int KSh = (H + 31) / 32;           // LDS-h k-chunks
    constexpr int HP  = (H < 32 ? 32 : H) + 8;   // padded h row stride (u16)
    constexpr int G4  = 4 * H;
    constexpr int NTH = 64 * UG;
    static_assert(D % 32 == 0 && T_SEQ % 4 == 0, "shape");

    const int tid  = threadIdx.x;
    const int ug   = tid >> 6;
    const int lane = tid & 63;
    const int lm   = lane & 15;
    const int lq   = lane >> 4;
    const int dir  = blockIdx.y;
    const int b0   = blockIdx.x * 16;

    const float* W  = dir ? Wb  : Wf;
    const float* U  = dir ? Ub  : Uf;
    const float* bg = dir ? bgb : bgf;

    __shared__ __align__(16) ushort_t hbuf[2 * 16 * HP];

    // ---- one-time weight prepack (pre-scaled). Frags identical for both modes. ----
    short8  aw[4][KSx];   // W^T frags
    short8  hw[4][KSh];   // U^T frags
    floatx4 bias4[4];     // persistent bias as MFMA C operand
#pragma unroll
    for (int g = 0; g < 4; g++) {
        const float sc = (g == 2) ? L2E2 : NL2E;
        const int ub = g * H + ug * 16;
        floatx4 b4;
#pragma unroll
        for (int r = 0; r < 4; r++)
            b4[r] = sc * bg[ub + (SW ? lq * 4 + r : lm)];   // classic: bcast over rows
        bias4[g] = b4;
        const int nc = ub + lm;
#pragma unroll
        for (int ks = 0; ks < KSx; ks++) {
            short8 f;
#pragma unroll
            for (int e = 0; e < 8; e++)
                f[e] = (short)f2bf(sc * W[(ks * 32 + lq * 8 + e) * G4 + nc]);
            aw[g][ks] = f;
        }
#pragma unroll
        for (int ks = 0; ks < KSh; ks++) {
            short8 f;
#pragma unroll
            for (int e = 0; e < 8; e++) {
                const int k = ks * 32 + lq * 8 + e;
                f[e] = (k < H) ? (short)f2bf(sc * U[k * G4 + nc]) : (short)0;
            }
            hw[g][ks] = f;
        }
    }

    for (int idx = tid; idx < 2 * 16 * HP; idx += NTH)
        hbuf[idx] = 0;   // h0 = 0; k-padding stays 0 forever

    float cst[4];        // holds 2log2e * c
    float hl[4];
#pragma unroll
    for (int r = 0; r < 4; r++) { cst[r] = 0.f; hl[r] = 0.f; }

    const int t0 = dir ? T_SEQ - 1 : 0;
    // stepping pointers (no per-step 64-bit muls); x loads identical across modes
    const float*    pxf = (const float*)xin + ((size_t)(b0 + lm) * T_SEQ + t0) * D + lq * 8;
    const ushort_t* pxb = (const ushort_t*)xin + ((size_t)t0 * BATCH + b0 + lm) * D + lq * 8;
    const long xstepf = dir ? -(long)D : (long)D;
    const long xstepb = (dir ? -(long)BATCH : (long)BATCH) * D;
    // output pointer, mode-dependent lane->element map
    ushort_t* pout;
    if constexpr (SW)
        pout = (ushort_t*)outp + ((size_t)t0 * BATCH + b0 + lm) * (2 * H) + dir * H +
               ug * 16 + lq * 4;
    else
        pout = (ushort_t*)outp + ((size_t)t0 * BATCH + b0 + lq * 4) * (2 * H) + dir * H +
               ug * 16 + lm;
    const long ostep = (dir ? -(long)BATCH : (long)BATCH) * (2 * H);

    // x prefetch ring, depth 4
    float4 rawf[4][2 * KSx];   // layer-1 path (fp32 input); DCE'd otherwise
    short8 rawb[4][KSx];       // bf16 path

    auto load_slot = [&](auto sl_) {
        constexpr int SL = decltype(sl_)::v;
        if (IS_FIRST) {
#pragma unroll
            for (int ks = 0; ks < KSx; ks++) {
                rawf[SL][2 * ks + 0] = *(const float4*)(pxf + ks * 32 + 0);
                rawf[SL][2 * ks + 1] = *(const float4*)(pxf + ks * 32 + 4);
            }
            pxf += xstepf;
        } else {
#pragma unroll
            for (int ks = 0; ks < KSx; ks++)
                rawb[SL][ks] = *(const short8*)(pxb + ks * 32);
            pxb += xstepb;
        }
    };

    load_slot(IC<0>{}); load_slot(IC<1>{}); load_slot(IC<2>{}); load_slot(IC<3>{});
    __syncthreads();   // hbuf zeros visible

    auto step = [&](auto p_, auto sl_, int s) {
        constexpr int P  = decltype(p_)::v;
        constexpr int SL = decltype(sl_)::v;

        // h frags from LDS (issued first; x-MFMAs overlap the lgkm latency)
        short8 fh[KSh];
#pragma unroll
        for (int ks = 0; ks < KSh; ks++)
            fh[ks] = *(const short8*)&hbuf[(P * 16 + lm) * HP + ks * 32 + lq * 8];

        // x frags from the register ring (packed fp32->bf16 conv on layer 1)
        short8 av[KSx];
        if (IS_FIRST) {
#pragma unroll
            for (int ks = 0; ks < KSx; ks++) {
                union { short8 s; uint_t u[4]; } f;
                const float* ra = (const float*)&rawf[SL][2 * ks];
#pragma unroll
                for (int e = 0; e < 4; e++) f.u[e] = pk_bf16(ra[2 * e], ra[2 * e + 1]);
                av[ks] = f.s;
            }
        } else {
#pragma unroll
            for (int ks = 0; ks < KSx; ks++) av[ks] = rawb[SL][ks];
        }

        floatx4 acc[4];
        // first x-MFMA carries the (persistent) bias as C — no per-step init movs
#pragma unroll
        for (int g = 0; g < 4; g++)
            acc[g] = SW
                ? __builtin_amdgcn_mfma_f32_16x16x32_bf16(aw[g][0], av[0], bias4[g], 0, 0, 0)
                : __builtin_amdgcn_mfma_f32_16x16x32_bf16(av[0], aw[g][0], bias4[g], 0, 0, 0);
#pragma unroll
        for (int ks = 1; ks < KSx; ks++)
#pragma unroll
            for (int g = 0; g < 4; g++)
                acc[g] = SW
                    ? __builtin_amdgcn_mfma_f32_16x16x32_bf16(aw[g][ks], av[ks], acc[g], 0, 0, 0)
                    : __builtin_amdgcn_mfma_f32_16x16x32_bf16(av[ks], aw[g][ks], acc[g], 0, 0, 0);

        if (s + 4 < T_SEQ) load_slot(sl_);   // refill consumed slot (uniform branch)

        // recurrent part last (shortest possible h -> MFMA distance)
#pragma unroll
        for (int ks = 0; ks < KSh; ks++)
#pragma unroll
            for (int g = 0; g < 4; g++)
                acc[g] = SW
                    ? __builtin_amdgcn_mfma_f32_16x16x32_bf16(hw[g][ks], fh[ks], acc[g], 0, 0, 0)
                    : __builtin_amdgcn_mfma_f32_16x16x32_bf16(fh[ks], hw[g][ks], acc[g], 0, 0, 0);

        // gates + c/h update (pre-scaled z; cst = 2log2e*c)
        float hv[4];
        if constexpr (ACT == 0) {
            // plain per-element rcp (best for L1: shortest chain latency)
#pragma unroll
            for (int r = 0; r < 4; r++) {
                const float gi = rcp_fast(1.0f + exp2_fast(acc[0][r]));
                const float gf = rcp_fast(1.0f + exp2_fast(acc[1][r]));
                const float gg = 1.0f - 2.0f * rcp_fast(1.0f + exp2_fast(acc[2][r]));
                const float go = rcp_fast(1.0f + exp2_fast(acc[3][r]));
                cst[r] = fmaf(gf, cst[r], L2E2 * (gi * gg));
                const float tc = 1.0f - 2.0f * rcp_fast(1.0f + exp2_fast(cst[r]));
                hv[r] = go * tc;
            }
        } else {
            // grouped-rcp (best for L2/L3: trans 40 -> 25 per step)
            float zi[4], zf[4], zg[4], zo[4];
#pragma unroll
            for (int r = 0; r < 4; r++) {
                zi[r] = acc[0][r]; zf[r] = acc[1][r];
                zg[r] = acc[2][r]; zo[r] = acc[3][r];
            }
            float gi[4], gf[4], gg[4], go[4];
            sig4(zi, gi); sig4(zf, gf); tanh4(zg, gg); sig4(zo, go);
            float cz[4];
#pragma unroll
            for (int r = 0; r < 4; r++) {
                cst[r] = fmaf(gf[r], cst[r], L2E2 * (gi[r] * gg[r]));
                cz[r] = cst[r];
            }
            float tc[4];
            tanh4(cz, tc);
#pragma unroll
            for (int r = 0; r < 4; r++) hv[r] = go[r] * tc[r];
        }

        if constexpr (SW) {
            const uint_t d0 = pk_bf16(hv[0], hv[1]);   // units +0,+1
            const uint_t d1 = pk_bf16(hv[2], hv[3]);   // units +2,+3
            uint2 wv; wv.x = d0; wv.y = d1;
            *(uint2*)&hbuf[((P ^ 1) * 16 + lm) * HP + ug * 16 + lq * 4] = wv;   // 1x b64
            if (SEQ_OUT) {
                uint2 ov; ov.x = d0; ov.y = d1;
                *(uint2*)&pout[0] = ov;                 // 1x dwordx2
            } else {
#pragma unroll
                for (int r = 0; r < 4; r++) hl[r] = hv[r];
            }
        } else {
            // classic: lane holds 4 ROWS (lq*4+r) of one unit column (ug*16+lm)
#pragma unroll
            for (int r = 0; r < 4; r++) {
                const ushort_t hw_ = f2bf(hv[r]);
                hbuf[((P ^ 1) * 16 + lq * 4 + r) * HP + ug * 16 + lm] = hw_;
                if (SEQ_OUT) pout[r * 2 * H] = hw_;
                else         hl[r] = hv[r];
            }
        }
        pout += ostep;
        if (UG > 1) sync_lds();   // lgkm-only; single-wave layers need no barrier
    };

    for (int s = 0; s < T_SEQ; s += 4) {
        step(IC<0>{}, IC<0>{}, s);
        step(IC<1>{}, IC<1>{}, s + 1);
        step(IC<0>{}, IC<2>{}, s + 2);
        step(IC<1>{}, IC<3>{}, s + 3);
    }

    if (!SEQ_OUT) {
        float* op = (float*)outp;
        if constexpr (SW) {
            float4 v4 = make_float4(hl[0], hl[1], hl[2], hl[3]);
            *(float4*)&op[(size_t)(b0 + lm) * (2 * H) + dir * H + ug * 16 + lq * 4] = v4;
        } else {
#pragma unroll
            for (int r = 0; r < 4; r++)
                op[(size_t)(b0 + lq * 4 + r) * (2 * H) + dir * H + ug * 16 + lm] = hl[r];
        }
    }
}

// Dense head: relu6(x@Wd1+bd1) @ Wd2 + bd2 -> softmax(2). One row per thread.
__global__ __launch_bounds__(256) void dense_head(
    const float* __restrict__ h3, const float* __restrict__ Wd1, const float* __restrict__ bd1,
    const float* __restrict__ Wd2, const float* __restrict__ bd2, float* __restrict__ out)
{
    const int b = blockIdx.x * blockDim.x + threadIdx.x;
    if (b >= BATCH) return;
    float x[32];
#pragma unroll
    for (int k = 0; k < 32; k++) x[k] = h3[b * 32 + k];
    float y[16];
#pragma unroll
    for (int jj = 0; jj < 16; jj++) {
        float a = bd1[jj];
#pragma unroll
        for (int k = 0; k < 32; k++) a = fmaf(x[k], Wd1[k * 16 + jj], a);
        y[jj] = fminf(fmaxf(a, 0.0f), 6.0f);
    }
    float l0 = bd2[0], l1 = bd2[1];
#pragma unroll
    for (int k = 0; k < 16; k++) {
        l0 = fmaf(y[k], Wd2[k * 2 + 0], l0);
        l1 = fmaf(y[k], Wd2[k * 2 + 1], l1);
    }
    const float m = fmaxf(l0, l1);
    const float e0 = __expf(l0 - m), e1 = __expf(l1 - m);
    const float inv = 1.0f / (e0 + e1);
    out[b * 2 + 0] = e0 * inv;
    out[b * 2 + 1] = e1 * inv;
}

extern "C" void kernel_launch(void* const* d_in, const int* in_sizes, int n_in,
                              void* d_out, int out_size, void* d_ws, size_t ws_size,
                              hipStream_t stream)
{
    const float* x   = (const float*)d_in[0];
    const float* W1f = (const float*)d_in[1];
    const float* U1f = (const float*)d_in[2];
    const float* b1f = (const float*)d_in[3];
    const float* W1b = (const float*)d_in[4];
    const float* U1b = (const float*)d_in[5];
    const float* b1b = (const float*)d_in[6];
    const float* W2f = (const float*)d_in[7];
    const float* U2f = (const float*)d_in[8];
    const float* b2f = (const float*)d_in[9];
    const float* W2b = (const float*)d_in[10];
    const float* U2b = (const float*)d_in[11];
    const float* b2b = (const float*)d_in[12];
    const float* W3f = (const float*)d_in[13];
    const float* U3f = (const float*)d_in[14];
    const float* b3f = (const float*)d_in[15];
    const float* W3b = (const float*)d_in[16];
    const float* U3b = (const float*)d_in[17];
    const float* b3b = (const float*)d_in[18];
    const float* Wd1 = (const float*)d_in[19];
    const float* bd1 = (const float*)d_in[20];
    const float* Wd2 = (const float*)d_in[21];
    const float* bd2 = (const float*)d_in[22];

    // workspace: the proven 96 MB + 128 KB footprint
    char* ws = (char*)d_ws;
    void*  l1out = (void*)ws;                                  // [T][B][128] bf16 = 64 MB
    void*  l2out = (void*)(ws + (size_t)64 * 1024 * 1024);     // [T][B][64]  bf16 = 32 MB
    float* h3    = (float*)(ws + (size_t)96 * 1024 * 1024);    // [B][32] fp32 = 128 KB
    float* out   = (float*)d_out;

    dim3 grid(BATCH / 16, 2);

    lstm_fused<64, 64, true, true, 0, 0>    // L1: CLASSIC 4-wave, PLAIN act (170.8)
        <<<grid, 256, 0, stream>>>(x, W1f, U1f, b1f, W1b, U1b, b1b, l1out);
    lstm_fused<128, 32, false, true, 1, 1>  // L2: SWAP-LDS 2-wave, grouped (~118)
        <<<grid, 128, 0, stream>>>(l1out, W2f, U2f, b2f, W2b, U2b, b2b, l2out);
    lstm_fused<64, 16, false, false, 1, 1>  // L3: SWAP-LDS 1-wave, grouped (~196)
        <<<grid, 64, 0, stream>>>(l2out, W3f, U3f, b3f, W3b, U3b, b3b, h3);
    dense_head<<<dim3(BATCH / 256), 256, 0, stream>>>(h3, Wd1, bd1, Wd2, bd2, out);
}

// Round 9
// 498.406 us; speedup vs baseline: 1.0167x; 1.0167x over previous
//
#include <hip/hip_runtime.h>
#include <hip/hip_bf16.h>

#define T_SEQ 256
#define BATCH 1024

typedef __attribute__((ext_vector_type(8))) short  short8;   // 8 bf16 (x32 MFMA frag)
typedef __attribute__((ext_vector_type(4))) float  floatx4;  // MFMA C/D frag
typedef unsigned short ushort_t;
typedef unsigned int   uint_t;

template <int P> struct IC { static constexpr int v = P; };

constexpr float NL2E = -1.4426950408889634f;   // -log2(e): sigmoid = rcp(1+exp2(z))
constexpr float L2E2 =  2.8853900817779268f;   // 2*log2(e): tanh = 1-2*rcp(1+exp2(x))

__device__ __forceinline__ float exp2_fast(float x) {
    float r; asm("v_exp_f32 %0, %1" : "=v"(r) : "v"(x)); return r;
}
__device__ __forceinline__ float rcp_fast(float x) {
    float r; asm("v_rcp_f32 %0, %1" : "=v"(r) : "v"(x)); return r;
}
__device__ __forceinline__ ushort_t f2bf(float f) {
    union { float f; uint_t u; } v; v.f = f;
    uint_t r = v.u + 0x7FFFu + ((v.u >> 16) & 1u);   // RNE
    return (ushort_t)(r >> 16);
}
__device__ __forceinline__ uint_t pk_bf16(float a, float b) {
    union { __hip_bfloat162 h; uint_t u; } v;
    v.h = __float22bfloat162_rn(make_float2(a, b));
    return v.u;
}
// Barrier WITHOUT vmcnt drain: LDS ordering only; global loads/stores stay in flight.
__device__ __forceinline__ void sync_lds() {
    asm volatile("s_waitcnt lgkmcnt(0)\n\ts_barrier" ::: "memory");
}

// ============================= Ledger (final, measured) ===========================
// This is the R6 kernel verbatim — the session's best WHOLE-KERNEL measurement
// (496.4us). R8 tested the composition {L1-plain + L2/L3-grouped} predicted faster
// from isolated deltas (L1 plain 171 vs grouped 182) and measured 506.7 — layer
// deltas inferred by subtraction carry ~±10us cross-round noise on the L2/L3 tail,
// so the measured-best artifact wins over the inferred-best composition.
// Falsified structural alternatives: REGH (R1, spills), dual-stream (R4, +100%
// work = +3% time), chain-split acc (R4, +115), xz-hoist (R5, null), bpermute
// h-exchange (R7, +18). Counters at convergence: HBM 9%, MfmaUtil 8%, VALU 25%,
// occupancy 5.5% — no classical roofline; the wall is 256 serial recurrence steps
// x ~650ns dependent MFMA+trans latency per step.
// =================================================================================

// 4 sigmoids from 4 prescaled logits with ONE rcp:
// A_r = 1+exp2(z_r); R=rcp(A0A1A2A3); 1/A0 = R*A1*(A2A3), etc.
__device__ __forceinline__ void sig4(const float z[4], float o[4]) {
    const float A0 = 1.0f + exp2_fast(z[0]);
    const float A1 = 1.0f + exp2_fast(z[1]);
    const float A2 = 1.0f + exp2_fast(z[2]);
    const float A3 = 1.0f + exp2_fast(z[3]);
    const float P01 = A0 * A1, P23 = A2 * A3;
    const float R   = rcp_fast(P01 * P23);
    const float R01 = R * P23;      // = 1/(A0*A1)
    const float R23 = R * P01;      // = 1/(A2*A3)
    o[0] = R01 * A1; o[1] = R01 * A0;
    o[2] = R23 * A3; o[3] = R23 * A2;
}
// 4 tanhs (arg prescaled by 2log2e): tanh = 1 - 2*sigmoid'(x)
__device__ __forceinline__ void tanh4(const float z[4], float o[4]) {
    float s[4]; sig4(z, s);
#pragma unroll
    for (int r = 0; r < 4; r++) o[r] = fmaf(-2.0f, s[r], 1.0f);
}

// Fused persistent LSTM layer — R3 structure + grouped-rcp activations.
template <int D, int H, bool IS_FIRST, bool SEQ_OUT, int MODE>
__global__ __launch_bounds__(64 * (H / 16), 1) void lstm_fused(
    const void* __restrict__ xin,
    const float* __restrict__ Wf, const float* __restrict__ Uf, const float* __restrict__ bgf,
    const float* __restrict__ Wb, const float* __restrict__ Ub, const float* __restrict__ bgb,
    void* __restrict__ outp)
{
    constexpr bool SW = (MODE >= 1);             // swapped operand order
    constexpr int UG  = H / 16;                  // waves per block
    constexpr int KSx = D / 32;                  // x k-chunks (16x16x32)
    constexpr int KSh = (H + 31) / 32;           // LDS-h k-chunks
    constexpr int HP  = (H < 32 ? 32 : H) + 8;   // padded h row stride (u16)
    constexpr int G4  = 4 * H;
    constexpr int NTH = 64 * UG;
    static_assert(D % 32 == 0 && T_SEQ % 4 == 0, "shape");

    const int tid  = threadIdx.x;
    const int ug   = tid >> 6;
    const int lane = tid & 63;
    const int lm   = lane & 15;
    const int lq   = lane >> 4;
    const int dir  = blockIdx.y;
    const int b0   = blockIdx.x * 16;

    const float* W  = dir ? Wb  : Wf;
    const float* U  = dir ? Ub  : Uf;
    const float* bg = dir ? bgb : bgf;

    __shared__ __align__(16) ushort_t hbuf[2 * 16 * HP];

    // ---- one-time weight prepack (pre-scaled). Frags identical for both modes. ----
    short8  aw[4][KSx];   // W^T frags
    short8  hw[4][KSh];   // U^T frags
    floatx4 bias4[4];     // persistent bias as MFMA C operand
#pragma unroll
    for (int g = 0; g < 4; g++) {
        const float sc = (g == 2) ? L2E2 : NL2E;
        const int ub = g * H + ug * 16;
        floatx4 b4;
#pragma unroll
        for (int r = 0; r < 4; r++)
            b4[r] = sc * bg[ub + (SW ? lq * 4 + r : lm)];   // classic: bcast over rows
        bias4[g] = b4;
        const int nc = ub + lm;
#pragma unroll
        for (int ks = 0; ks < KSx; ks++) {
            short8 f;
#pragma unroll
            for (int e = 0; e < 8; e++)
                f[e] = (short)f2bf(sc * W[(ks * 32 + lq * 8 + e) * G4 + nc]);
            aw[g][ks] = f;
        }
#pragma unroll
        for (int ks = 0; ks < KSh; ks++) {
            short8 f;
#pragma unroll
            for (int e = 0; e < 8; e++) {
                const int k = ks * 32 + lq * 8 + e;
                f[e] = (k < H) ? (short)f2bf(sc * U[k * G4 + nc]) : (short)0;
            }
            hw[g][ks] = f;
        }
    }

    for (int idx = tid; idx < 2 * 16 * HP; idx += NTH)
        hbuf[idx] = 0;   // h0 = 0; k-padding stays 0 forever

    float cst[4];        // holds 2log2e * c
    float hl[4];
#pragma unroll
    for (int r = 0; r < 4; r++) { cst[r] = 0.f; hl[r] = 0.f; }

    const int t0 = dir ? T_SEQ - 1 : 0;
    // stepping pointers (no per-step 64-bit muls); x loads identical across modes
    const float*    pxf = (const float*)xin + ((size_t)(b0 + lm) * T_SEQ + t0) * D + lq * 8;
    const ushort_t* pxb = (const ushort_t*)xin + ((size_t)t0 * BATCH + b0 + lm) * D + lq * 8;
    const long xstepf = dir ? -(long)D : (long)D;
    const long xstepb = (dir ? -(long)BATCH : (long)BATCH) * D;
    // output pointer, mode-dependent lane->element map
    ushort_t* pout;
    if constexpr (SW)
        pout = (ushort_t*)outp + ((size_t)t0 * BATCH + b0 + lm) * (2 * H) + dir * H +
               ug * 16 + lq * 4;
    else
        pout = (ushort_t*)outp + ((size_t)t0 * BATCH + b0 + lq * 4) * (2 * H) + dir * H +
               ug * 16 + lm;
    const long ostep = (dir ? -(long)BATCH : (long)BATCH) * (2 * H);

    // x prefetch ring, depth 4
    float4 rawf[4][2 * KSx];   // layer-1 path (fp32 input); DCE'd otherwise
    short8 rawb[4][KSx];       // bf16 path

    auto load_slot = [&](auto sl_) {
        constexpr int SL = decltype(sl_)::v;
        if (IS_FIRST) {
#pragma unroll
            for (int ks = 0; ks < KSx; ks++) {
                rawf[SL][2 * ks + 0] = *(const float4*)(pxf + ks * 32 + 0);
                rawf[SL][2 * ks + 1] = *(const float4*)(pxf + ks * 32 + 4);
            }
            pxf += xstepf;
        } else {
#pragma unroll
            for (int ks = 0; ks < KSx; ks++)
                rawb[SL][ks] = *(const short8*)(pxb + ks * 32);
            pxb += xstepb;
        }
    };

    load_slot(IC<0>{}); load_slot(IC<1>{}); load_slot(IC<2>{}); load_slot(IC<3>{});
    __syncthreads();   // hbuf zeros visible

    auto step = [&](auto p_, auto sl_, int s) {
        constexpr int P  = decltype(p_)::v;
        constexpr int SL = decltype(sl_)::v;

        // h frags from LDS (issued first; x-MFMAs overlap the lgkm latency)
        short8 fh[KSh];
#pragma unroll
        for (int ks = 0; ks < KSh; ks++)
            fh[ks] = *(const short8*)&hbuf[(P * 16 + lm) * HP + ks * 32 + lq * 8];

        // x frags from the register ring (packed fp32->bf16 conv on layer 1)
        short8 av[KSx];
        if (IS_FIRST) {
#pragma unroll
            for (int ks = 0; ks < KSx; ks++) {
                union { short8 s; uint_t u[4]; } f;
                const float* ra = (const float*)&rawf[SL][2 * ks];
#pragma unroll
                for (int e = 0; e < 4; e++) f.u[e] = pk_bf16(ra[2 * e], ra[2 * e + 1]);
                av[ks] = f.s;
            }
        } else {
#pragma unroll
            for (int ks = 0; ks < KSx; ks++) av[ks] = rawb[SL][ks];
        }

        floatx4 acc[4];
        // first x-MFMA carries the (persistent) bias as C — no per-step init movs
#pragma unroll
        for (int g = 0; g < 4; g++)
            acc[g] = SW
                ? __builtin_amdgcn_mfma_f32_16x16x32_bf16(aw[g][0], av[0], bias4[g], 0, 0, 0)
                : __builtin_amdgcn_mfma_f32_16x16x32_bf16(av[0], aw[g][0], bias4[g], 0, 0, 0);
#pragma unroll
        for (int ks = 1; ks < KSx; ks++)
#pragma unroll
            for (int g = 0; g < 4; g++)
                acc[g] = SW
                    ? __builtin_amdgcn_mfma_f32_16x16x32_bf16(aw[g][ks], av[ks], acc[g], 0, 0, 0)
                    : __builtin_amdgcn_mfma_f32_16x16x32_bf16(av[ks], aw[g][ks], acc[g], 0, 0, 0);

        if (s + 4 < T_SEQ) load_slot(sl_);   // refill consumed slot (uniform branch)

        // recurrent part last (shortest possible h -> MFMA distance)
#pragma unroll
        for (int ks = 0; ks < KSh; ks++)
#pragma unroll
            for (int g = 0; g < 4; g++)
                acc[g] = SW
                    ? __builtin_amdgcn_mfma_f32_16x16x32_bf16(hw[g][ks], fh[ks], acc[g], 0, 0, 0)
                    : __builtin_amdgcn_mfma_f32_16x16x32_bf16(fh[ks], hw[g][ks], acc[g], 0, 0, 0);

        // gates + c/h update — grouped-rcp activations (trans 40 -> 25 per step)
        float zi[4], zf[4], zg[4], zo[4];
#pragma unroll
        for (int r = 0; r < 4; r++) {
            zi[r] = acc[0][r]; zf[r] = acc[1][r];
            zg[r] = acc[2][r]; zo[r] = acc[3][r];
        }
        float gi[4], gf[4], gg[4], go[4];
        sig4(zi, gi); sig4(zf, gf); tanh4(zg, gg); sig4(zo, go);
        float cz[4];
#pragma unroll
        for (int r = 0; r < 4; r++) {
            cst[r] = fmaf(gf[r], cst[r], L2E2 * (gi[r] * gg[r]));
            cz[r] = cst[r];
        }
        float tc[4];
        tanh4(cz, tc);
        float hv[4];
#pragma unroll
        for (int r = 0; r < 4; r++) hv[r] = go[r] * tc[r];

        if constexpr (SW) {
            const uint_t d0 = pk_bf16(hv[0], hv[1]);   // units +0,+1
            const uint_t d1 = pk_bf16(hv[2], hv[3]);   // units +2,+3
            uint2 wv; wv.x = d0; wv.y = d1;
            *(uint2*)&hbuf[((P ^ 1) * 16 + lm) * HP + ug * 16 + lq * 4] = wv;   // 1x b64
            if (SEQ_OUT) {
                uint2 ov; ov.x = d0; ov.y = d1;
                *(uint2*)&pout[0] = ov;                 // 1x dwordx2
            } else {
#pragma unroll
                for (int r = 0; r < 4; r++) hl[r] = hv[r];
            }
        } else {
            // classic: lane holds 4 ROWS (lq*4+r) of one unit column (ug*16+lm)
#pragma unroll
            for (int r = 0; r < 4; r++) {
                const ushort_t hw_ = f2bf(hv[r]);
                hbuf[((P ^ 1) * 16 + lq * 4 + r) * HP + ug * 16 + lm] = hw_;
                if (SEQ_OUT) pout[r * 2 * H] = hw_;
                else         hl[r] = hv[r];
            }
        }
        pout += ostep;
        if (UG > 1) sync_lds();   // lgkm-only; single-wave layers need no barrier
    };

    for (int s = 0; s < T_SEQ; s += 4) {
        step(IC<0>{}, IC<0>{}, s);
        step(IC<1>{}, IC<1>{}, s + 1);
        step(IC<0>{}, IC<2>{}, s + 2);
        step(IC<1>{}, IC<3>{}, s + 3);
    }

    if (!SEQ_OUT) {
        float* op = (float*)outp;
        if constexpr (SW) {
            float4 v4 = make_float4(hl[0], hl[1], hl[2], hl[3]);
            *(float4*)&op[(size_t)(b0 + lm) * (2 * H) + dir * H + ug * 16 + lq * 4] = v4;
        } else {
#pragma unroll
            for (int r = 0; r < 4; r++)
                op[(size_t)(b0 + lq * 4 + r) * (2 * H) + dir * H + ug * 16 + lm] = hl[r];
        }
    }
}

// Dense head: relu6(x@Wd1+bd1) @ Wd2 + bd2 -> softmax(2). One row per thread.
__global__ __launch_bounds__(256) void dense_head(
    const float* __restrict__ h3, const float* __restrict__ Wd1, const float* __restrict__ bd1,
    const float* __restrict__ Wd2, const float* __restrict__ bd2, float* __restrict__ out)
{
    const int b = blockIdx.x * blockDim.x + threadIdx.x;
    if (b >= BATCH) return;
    float x[32];
#pragma unroll
    for (int k = 0; k < 32; k++) x[k] = h3[b * 32 + k];
    float y[16];
#pragma unroll
    for (int jj = 0; jj < 16; jj++) {
        float a = bd1[jj];
#pragma unroll
        for (int k = 0; k < 32; k++) a = fmaf(x[k], Wd1[k * 16 + jj], a);
        y[jj] = fminf(fmaxf(a, 0.0f), 6.0f);
    }
    float l0 = bd2[0], l1 = bd2[1];
#pragma unroll
    for (int k = 0; k < 16; k++) {
        l0 = fmaf(y[k], Wd2[k * 2 + 0], l0);
        l1 = fmaf(y[k], Wd2[k * 2 + 1], l1);
    }
    const float m = fmaxf(l0, l1);
    const float e0 = __expf(l0 - m), e1 = __expf(l1 - m);
    const float inv = 1.0f / (e0 + e1);
    out[b * 2 + 0] = e0 * inv;
    out[b * 2 + 1] = e1 * inv;
}

extern "C" void kernel_launch(void* const* d_in, const int* in_sizes, int n_in,
                              void* d_out, int out_size, void* d_ws, size_t ws_size,
                              hipStream_t stream)
{
    const float* x   = (const float*)d_in[0];
    const float* W1f = (const float*)d_in[1];
    const float* U1f = (const float*)d_in[2];
    const float* b1f = (const float*)d_in[3];
    const float* W1b = (const float*)d_in[4];
    const float* U1b = (const float*)d_in[5];
    const float* b1b = (const float*)d_in[6];
    const float* W2f = (const float*)d_in[7];
    const float* U2f = (const float*)d_in[8];
    const float* b2f = (const float*)d_in[9];
    const float* W2b = (const float*)d_in[10];
    const float* U2b = (const float*)d_in[11];
    const float* b2b = (const float*)d_in[12];
    const float* W3f = (const float*)d_in[13];
    const float* U3f = (const float*)d_in[14];
    const float* b3f = (const float*)d_in[15];
    const float* W3b = (const float*)d_in[16];
    const float* U3b = (const float*)d_in[17];
    const float* b3b = (const float*)d_in[18];
    const float* Wd1 = (const float*)d_in[19];
    const float* bd1 = (const float*)d_in[20];
    const float* Wd2 = (const float*)d_in[21];
    const float* bd2 = (const float*)d_in[22];

    // workspace: the proven 96 MB + 128 KB footprint
    char* ws = (char*)d_ws;
    void*  l1out = (void*)ws;                                  // [T][B][128] bf16 = 64 MB
    void*  l2out = (void*)(ws + (size_t)64 * 1024 * 1024);     // [T][B][64]  bf16 = 32 MB
    float* h3    = (float*)(ws + (size_t)96 * 1024 * 1024);    // [B][32] fp32 = 128 KB
    float* out   = (float*)d_out;

    dim3 grid(BATCH / 16, 2);

    lstm_fused<64, 64, true, true, 0>      // CLASSIC, 4 waves (best measured for L1)
        <<<grid, 256, 0, stream>>>(x, W1f, U1f, b1f, W1b, U1b, b1b, l1out);
    lstm_fused<128, 32, false, true, 1>    // SWAP-LDS, 2 waves (best measured for L2)
        <<<grid, 128, 0, stream>>>(l1out, W2f, U2f, b2f, W2b, U2b, b2b, l2out);
    lstm_fused<64, 16, false, false, 1>    // SWAP-LDS, 1 wave, barrier-free (best L3)
        <<<grid, 64, 0, stream>>>(l2out, W3f, U3f, b3f, W3b, U3b, b3b, h3);
    dense_head<<<dim3(BATCH / 256), 256, 0, stream>>>(h3, Wd1, bd1, Wd2, bd2, out);
}